// Round 2
// baseline (228.379 us; speedup 1.0000x reference)
//
#include <hip/hip_runtime.h>
#include <hip/hip_bf16.h>

// out[i] = 0.999f * a[i*K + (int)z[i*D + attr_index]]
// B = 4194304, D = 32, K = 16.
//
// K=16 floats == one 64B HBM line, so the whole a-row is fetched regardless.
// Load it fully (4 x float4, coalesced stream), select in-register via a
// cndmask tree -> breaks the z->a dependent-load chain, same HBM bytes.

#define D_DIM 32
#define K_DIM 16
#define SCALE 0.999f
#define ROWS  4   // rows per thread -> float4 stores

__global__ __launch_bounds__(256) void gather_valuation_kernel(
    const float* __restrict__ z,
    const float* __restrict__ a,
    const int* __restrict__ attr_p,
    float* __restrict__ out,
    int B)
{
    const int attr = attr_p[0];
    const long t    = (long)blockIdx.x * blockDim.x + threadIdx.x;
    const long base = t * ROWS;
    if (base >= B) return;

    // 4 independent scattered z loads (column attr, stride 128B)
    float zv[ROWS];
#pragma unroll
    for (int j = 0; j < ROWS; ++j)
        zv[j] = z[(base + j) * D_DIM + attr];

    // Speculatively load each full a-row: 4 x float4 per row, issued
    // independently of the z loads. Perfectly coalesced sequential stream.
    const float4* __restrict__ a4 = (const float4*)a;
    float4 q[ROWS][4];
#pragma unroll
    for (int j = 0; j < ROWS; ++j) {
#pragma unroll
        for (int c = 0; c < 4; ++c)
            q[j][c] = a4[(base + j) * (K_DIM / 4) + c];
    }

    // In-register 16-way select per row (v_cndmask tree, all indices static)
    float4 res;
#pragma unroll
    for (int j = 0; j < ROWS; ++j) {
        const int idx = (int)zv[j];
        const float4 qa = (idx & 8) ? ((idx & 4) ? q[j][3] : q[j][2])
                                    : ((idx & 4) ? q[j][1] : q[j][0]);
        const float  x  = (idx & 2) ? ((idx & 1) ? qa.w : qa.z)
                                    : ((idx & 1) ? qa.y : qa.x);
        ((float*)&res)[j] = x * SCALE;
    }

    // Coalesced 16B/lane store
    *(float4*)(out + base) = res;
}

extern "C" void kernel_launch(void* const* d_in, const int* in_sizes, int n_in,
                              void* d_out, int out_size, void* d_ws, size_t ws_size,
                              hipStream_t stream)
{
    const float* z    = (const float*)d_in[0];
    const float* a    = (const float*)d_in[1];
    const int*   attr = (const int*)d_in[2];
    float*       out  = (float*)d_out;

    const int B = out_size;  // 4194304, divisible by 256*ROWS

    const int block = 256;
    const int grid  = (B + block * ROWS - 1) / (block * ROWS);  // 4096

    gather_valuation_kernel<<<grid, block, 0, stream>>>(z, a, attr, out, B);
}

// Round 3
// 147.182 us; speedup vs baseline: 1.5517x; 1.5517x over previous
//
#include <hip/hip_runtime.h>
#include <hip/hip_bf16.h>

// out[i] = 0.999f * a[i*K + (int)z[i*D + attr_index]]
// B = 4194304, D = 32, K = 16.
//
// Request/latency-bound gather. Strategy: minimal requests per element
// (one 4B z load, one 4B a load, 1/4 of a float4 store) + 8-deep ILP
// batching per thread so 16 independent loads are in flight per thread.

#define D_DIM 32
#define K_DIM 16
#define SCALE 0.999f
#define ROWS  8   // rows per thread

__global__ __launch_bounds__(256) void gather_valuation_kernel(
    const float* __restrict__ z,
    const float* __restrict__ a,
    const int* __restrict__ attr_p,
    float* __restrict__ out,
    int B)
{
    const int attr = attr_p[0];
    const long t    = (long)blockIdx.x * blockDim.x + threadIdx.x;
    const long base = t * ROWS;
    if (base >= B) return;

    // 8 independent z column loads (4B each, stride 128B)
    float zv[ROWS];
#pragma unroll
    for (int j = 0; j < ROWS; ++j)
        zv[j] = z[(base + j) * D_DIM + attr];

    // 8 independent a gathers (4B each); compiler issues gather j as soon
    // as zv[j] lands (incremental vmcnt waits), keeping the pipe full.
    float g[ROWS];
#pragma unroll
    for (int j = 0; j < ROWS; ++j) {
        const int idx = (int)zv[j];
        g[j] = a[(base + j) * K_DIM + idx];
    }

    // Two coalesced float4 stores (32B per lane total)
    float4 r0, r1;
    r0.x = g[0] * SCALE; r0.y = g[1] * SCALE;
    r0.z = g[2] * SCALE; r0.w = g[3] * SCALE;
    r1.x = g[4] * SCALE; r1.y = g[5] * SCALE;
    r1.z = g[6] * SCALE; r1.w = g[7] * SCALE;
    float4* o4 = (float4*)(out + base);
    o4[0] = r0;
    o4[1] = r1;
}

extern "C" void kernel_launch(void* const* d_in, const int* in_sizes, int n_in,
                              void* d_out, int out_size, void* d_ws, size_t ws_size,
                              hipStream_t stream)
{
    const float* z    = (const float*)d_in[0];
    const float* a    = (const float*)d_in[1];
    const int*   attr = (const int*)d_in[2];
    float*       out  = (float*)d_out;

    const int B = out_size;  // 4194304 = 256 * 8 * 2048

    const int block = 256;
    const int grid  = (B + block * ROWS - 1) / (block * ROWS);  // 2048

    gather_valuation_kernel<<<grid, block, 0, stream>>>(z, a, attr, out, B);
}

// Round 5
// 135.677 us; speedup vs baseline: 1.6833x; 1.0848x over previous
//
#include <hip/hip_runtime.h>
#include <hip/hip_bf16.h>

// out[i] = 0.999f * a[i*K + (int)z[i*D + attr_index]]
// B = 4194304, D = 32, K = 16.
//
// Memory-throughput-bound gather (~784 MB of 128B-line traffic).
// Round-3 structure (minimal requests, 8 rows/thread) + non-temporal
// hints: this data streams exactly once, so skip L2 allocation.
// NT store needs a native vector type (clang ext_vector), not float4.

#define D_DIM 32
#define K_DIM 16
#define SCALE 0.999f
#define ROWS  8   // rows per thread

typedef float f32x4 __attribute__((ext_vector_type(4)));

__global__ __launch_bounds__(256) void gather_valuation_kernel(
    const float* __restrict__ z,
    const float* __restrict__ a,
    const int* __restrict__ attr_p,
    float* __restrict__ out,
    int B)
{
    const int attr = attr_p[0];
    const long t    = (long)blockIdx.x * blockDim.x + threadIdx.x;
    const long base = t * ROWS;
    if (base >= B) return;

    // 8 independent z column loads (4B each, stride 128B), non-temporal
    float zv[ROWS];
#pragma unroll
    for (int j = 0; j < ROWS; ++j)
        zv[j] = __builtin_nontemporal_load(&z[(base + j) * D_DIM + attr]);

    // 8 independent a gathers (4B each), non-temporal
    float g[ROWS];
#pragma unroll
    for (int j = 0; j < ROWS; ++j) {
        const int idx = (int)zv[j];
        g[j] = __builtin_nontemporal_load(&a[(base + j) * K_DIM + idx]);
    }

    // Two coalesced 16B stores, non-temporal (native vector type)
    f32x4 r0, r1;
    r0.x = g[0] * SCALE; r0.y = g[1] * SCALE;
    r0.z = g[2] * SCALE; r0.w = g[3] * SCALE;
    r1.x = g[4] * SCALE; r1.y = g[5] * SCALE;
    r1.z = g[6] * SCALE; r1.w = g[7] * SCALE;
    f32x4* o4 = (f32x4*)(out + base);
    __builtin_nontemporal_store(r0, &o4[0]);
    __builtin_nontemporal_store(r1, &o4[1]);
}

extern "C" void kernel_launch(void* const* d_in, const int* in_sizes, int n_in,
                              void* d_out, int out_size, void* d_ws, size_t ws_size,
                              hipStream_t stream)
{
    const float* z    = (const float*)d_in[0];
    const float* a    = (const float*)d_in[1];
    const int*   attr = (const int*)d_in[2];
    float*       out  = (float*)d_out;

    const int B = out_size;  // 4194304 = 256 * 8 * 2048

    const int block = 256;
    const int grid  = (B + block * ROWS - 1) / (block * ROWS);  // 2048

    gather_valuation_kernel<<<grid, block, 0, stream>>>(z, a, attr, out, B);
}